// Round 1
// baseline (312.199 us; speedup 1.0000x reference)
//
#include <hip/hip_runtime.h>
#include <cstdint>
#include <cstddef>

#define N_NODES 50000
#define N_EDGES 800000
#define CAP 64   // max in-degree capacity; Binomial(800k,1/50k) mean 16 -> P(>64) ~ 1e-20

// ---------------- bucket-CSR build ----------------
__global__ __launch_bounds__(256) void k_build(const int* __restrict__ src,
                                               const int* __restrict__ dst,
                                               int* __restrict__ cnt,
                                               int* __restrict__ bucket) {
    int e = blockIdx.x * 256 + threadIdx.x;
    if (e >= N_EDGES) return;
    int d = dst[e];
    int p = atomicAdd(&cnt[d], 1);
    if (p < CAP) bucket[(size_t)d * CAP + p] = src[e];
}

// ---------------- pull-style segment mean: one wave per node ----------------
__global__ __launch_bounds__(256) void k_aggregate(const float* __restrict__ h,
                                                   const int* __restrict__ cnt,
                                                   const int* __restrict__ bucket,
                                                   float* __restrict__ out) {
    int wave = (int)((blockIdx.x * 256u + threadIdx.x) >> 6);
    int lane = threadIdx.x & 63;
    if (wave >= N_NODES) return;
    int deg = cnt[wave];
    int n = deg < CAP ? deg : CAP;
    const int* bk = bucket + (size_t)wave * CAP;
    float ax = 0.f, ay = 0.f;
    for (int e = 0; e < n; ++e) {
        int s = bk[e];
        float2 v = ((const float2*)(h + (size_t)s * 128))[lane];
        ax += v.x; ay += v.y;
    }
    float inv = 1.0f / fmaxf((float)deg, 1.0f);
    float2 r; r.x = ax * inv; r.y = ay * inv;
    ((float2*)(out + (size_t)wave * 128))[lane] = r;
}

// ---------------- fused layer-1 GEMM: h1 = relu(x@Ws + hn@Wn + b) ----------------
__global__ __launch_bounds__(256) void k_gemm1(const float* __restrict__ x,
                                               const float* __restrict__ hn,
                                               const float* __restrict__ Ws,
                                               const float* __restrict__ Wn,
                                               const float* __restrict__ b,
                                               float* __restrict__ out) {
    __shared__ float xs[32][128];
    __shared__ float hs[32][128];
    int tid = threadIdx.x;
    int row0 = blockIdx.x * 32;
    // stage 32 rows of x and hn (float4-vectorized, 256 threads x 4 iters)
    for (int i = tid; i < 32 * 32; i += 256) {
        int r = i >> 5, c4 = i & 31;
        int gr = row0 + r;
        float4 vx = make_float4(0.f, 0.f, 0.f, 0.f);
        float4 vh = vx;
        if (gr < N_NODES) {
            vx = ((const float4*)(x + (size_t)gr * 128))[c4];
            vh = ((const float4*)(hn + (size_t)gr * 128))[c4];
        }
        ((float4*)xs[r])[c4] = vx;
        ((float4*)hs[r])[c4] = vh;
    }
    __syncthreads();

    int tc = tid & 31;   // column group: cols tc*4 .. tc*4+3
    int tr = tid >> 5;   // row group: rows tr*4 .. tr*4+3
    float acc[4][4] = {};
    for (int k = 0; k < 128; k += 4) {
        float4 ws4[4], wn4[4];
#pragma unroll
        for (int kk = 0; kk < 4; ++kk) {
            ws4[kk] = ((const float4*)(Ws + (size_t)(k + kk) * 128))[tc];
            wn4[kk] = ((const float4*)(Wn + (size_t)(k + kk) * 128))[tc];
        }
        float4 xv[4], hv[4];
#pragma unroll
        for (int rr = 0; rr < 4; ++rr) {
            xv[rr] = *(const float4*)&xs[tr * 4 + rr][k];
            hv[rr] = *(const float4*)&hs[tr * 4 + rr][k];
        }
#pragma unroll
        for (int kk = 0; kk < 4; ++kk) {
#pragma unroll
            for (int rr = 0; rr < 4; ++rr) {
                float xvv = ((const float*)&xv[rr])[kk];
                float hvv = ((const float*)&hv[rr])[kk];
                acc[rr][0] += xvv * ((const float*)&ws4[kk])[0] + hvv * ((const float*)&wn4[kk])[0];
                acc[rr][1] += xvv * ((const float*)&ws4[kk])[1] + hvv * ((const float*)&wn4[kk])[1];
                acc[rr][2] += xvv * ((const float*)&ws4[kk])[2] + hvv * ((const float*)&wn4[kk])[2];
                acc[rr][3] += xvv * ((const float*)&ws4[kk])[3] + hvv * ((const float*)&wn4[kk])[3];
            }
        }
    }
    float4 bias = ((const float4*)b)[tc];
#pragma unroll
    for (int rr = 0; rr < 4; ++rr) {
        int gr = row0 + tr * 4 + rr;
        if (gr < N_NODES) {
            float4 o;
            o.x = fmaxf(acc[rr][0] + bias.x, 0.f);
            o.y = fmaxf(acc[rr][1] + bias.y, 0.f);
            o.z = fmaxf(acc[rr][2] + bias.z, 0.f);
            o.w = fmaxf(acc[rr][3] + bias.w, 0.f);
            ((float4*)(out + (size_t)gr * 128))[tc] = o;
        }
    }
}

// ---------------- fold layer-2 weights through the final projection ----------------
// wc layout: [0..255]   Wcs[k][c] = sum_j W2s[k][j]*Wf[j][c]
//            [256..511] Wcn[k][c] = sum_j W2n[k][j]*Wf[j][c]
//            [512..513] bc[c]     = sum_j b2[j]*Wf[j][c] + bf[c]
__global__ void k_combine(const float* __restrict__ W2s, const float* __restrict__ W2n,
                          const float* __restrict__ b2, const float* __restrict__ Wf,
                          const float* __restrict__ bf, float* __restrict__ wc) {
    int t = threadIdx.x;   // 256 threads
    int k = t >> 1, c = t & 1;
    float s1 = 0.f, s2 = 0.f;
    for (int j = 0; j < 128; ++j) {
        float wf = Wf[j * 2 + c];
        s1 += W2s[k * 128 + j] * wf;
        s2 += W2n[k * 128 + j] * wf;
    }
    wc[k * 2 + c] = s1;
    wc[256 + k * 2 + c] = s2;
    if (t < 2) {
        float s = bf[t];
        for (int j = 0; j < 128; ++j) s += b2[j] * Wf[j * 2 + t];
        wc[512 + t] = s;
    }
}

// ---------------- final: out[n][c] = h1[n]:@Wcs[:,c] + hn2[n]:@Wcn[:,c] + bc[c] ----------------
__global__ __launch_bounds__(256) void k_final(const float* __restrict__ h1,
                                               const float* __restrict__ hn2,
                                               const float* __restrict__ wc,
                                               float* __restrict__ out) {
    int wave = (int)((blockIdx.x * 256u + threadIdx.x) >> 6);
    int lane = threadIdx.x & 63;
    if (wave >= N_NODES) return;
    float2 hv = ((const float2*)(h1 + (size_t)wave * 128))[lane];   // k = 2*lane, 2*lane+1
    float2 nv = ((const float2*)(hn2 + (size_t)wave * 128))[lane];
    float2 ws0 = ((const float2*)wc)[2 * lane];        // Wcs[2l][0..1]
    float2 ws1 = ((const float2*)wc)[2 * lane + 1];    // Wcs[2l+1][0..1]
    float2 wn0 = ((const float2*)(wc + 256))[2 * lane];
    float2 wn1 = ((const float2*)(wc + 256))[2 * lane + 1];
    float p0 = hv.x * ws0.x + hv.y * ws1.x + nv.x * wn0.x + nv.y * wn1.x;
    float p1 = hv.x * ws0.y + hv.y * ws1.y + nv.x * wn0.y + nv.y * wn1.y;
#pragma unroll
    for (int off = 32; off >= 1; off >>= 1) {
        p0 += __shfl_xor(p0, off, 64);
        p1 += __shfl_xor(p1, off, 64);
    }
    if (lane == 0) {
        out[(size_t)wave * 2 + 0] = p0 + wc[512];
        out[(size_t)wave * 2 + 1] = p1 + wc[513];
    }
}

extern "C" void kernel_launch(void* const* d_in, const int* in_sizes, int n_in,
                              void* d_out, int out_size, void* d_ws, size_t ws_size,
                              hipStream_t stream) {
    const float* x   = (const float*)d_in[0];
    const int* esrc  = (const int*)d_in[1];
    const int* edst  = (const int*)d_in[2];
    const float* W1s = (const float*)d_in[3];
    const float* W1n = (const float*)d_in[4];
    const float* b1  = (const float*)d_in[5];
    const float* W2s = (const float*)d_in[6];
    const float* W2n = (const float*)d_in[7];
    const float* b2  = (const float*)d_in[8];
    const float* Wf  = (const float*)d_in[9];
    const float* bf  = (const float*)d_in[10];
    float* out = (float*)d_out;

    char* ws = (char*)d_ws;
    auto alloc = [&](size_t bytes) {
        char* p = ws;
        ws += (bytes + 255) & ~(size_t)255;
        return p;
    };
    int*   cnt    = (int*)  alloc((size_t)N_NODES * 4);
    int*   bucket = (int*)  alloc((size_t)N_NODES * CAP * 4);
    float* hn     = (float*)alloc((size_t)N_NODES * 128 * 4);
    float* h1     = (float*)alloc((size_t)N_NODES * 128 * 4);
    float* wc     = (float*)alloc(1024 * 4);

    hipMemsetAsync(cnt, 0, (size_t)N_NODES * 4, stream);
    k_build<<<(N_EDGES + 255) / 256, 256, 0, stream>>>(esrc, edst, cnt, bucket);
    k_aggregate<<<(N_NODES + 3) / 4, 256, 0, stream>>>(x, cnt, bucket, hn);
    k_gemm1<<<(N_NODES + 31) / 32, 256, 0, stream>>>(x, hn, W1s, W1n, b1, h1);
    k_combine<<<1, 256, 0, stream>>>(W2s, W2n, b2, Wf, bf, wc);
    k_aggregate<<<(N_NODES + 3) / 4, 256, 0, stream>>>(h1, cnt, bucket, hn);
    k_final<<<(N_NODES + 3) / 4, 256, 0, stream>>>(h1, hn, wc, out);
}

// Round 2
// 242.813 us; speedup vs baseline: 1.2858x; 1.2858x over previous
//
#include <hip/hip_runtime.h>
#include <cstdint>
#include <cstddef>

#define N_NODES 50000
#define N_EDGES 800000
#define CAP 64   // max in-degree capacity; Binomial(800k,1/50k) mean 16 -> P(>64) ~ 1e-20

// ---------------- bucket-CSR build ----------------
__global__ __launch_bounds__(256) void k_build(const int* __restrict__ src,
                                               const int* __restrict__ dst,
                                               int* __restrict__ cnt,
                                               int* __restrict__ bucket) {
    int e = blockIdx.x * 256 + threadIdx.x;
    if (e >= N_EDGES) return;
    int d = dst[e];
    int p = atomicAdd(&cnt[d], 1);
    if (p < CAP) bucket[(size_t)d * CAP + p] = src[e];
}

// ---------------- pull-style segment mean: one wave per node, 8-way MLP ----------------
__global__ __launch_bounds__(256) void k_aggregate(const float* __restrict__ h,
                                                   const int* __restrict__ cnt,
                                                   const int* __restrict__ bucket,
                                                   float* __restrict__ out) {
    int wave = (int)((blockIdx.x * 256u + threadIdx.x) >> 6);
    int lane = threadIdx.x & 63;
    if (wave >= N_NODES) return;
    int deg = cnt[wave];
    int n = deg < CAP ? deg : CAP;
    const int* bk = bucket + (size_t)wave * CAP;
    float ax0 = 0.f, ay0 = 0.f, ax1 = 0.f, ay1 = 0.f;
    float ax2 = 0.f, ay2 = 0.f, ax3 = 0.f, ay3 = 0.f;
    int e = 0;
    for (; e + 8 <= n; e += 8) {
        int4 ia = *(const int4*)(bk + e);
        int4 ib = *(const int4*)(bk + e + 4);
        float2 v0 = ((const float2*)(h + (size_t)ia.x * 128))[lane];
        float2 v1 = ((const float2*)(h + (size_t)ia.y * 128))[lane];
        float2 v2 = ((const float2*)(h + (size_t)ia.z * 128))[lane];
        float2 v3 = ((const float2*)(h + (size_t)ia.w * 128))[lane];
        float2 v4 = ((const float2*)(h + (size_t)ib.x * 128))[lane];
        float2 v5 = ((const float2*)(h + (size_t)ib.y * 128))[lane];
        float2 v6 = ((const float2*)(h + (size_t)ib.z * 128))[lane];
        float2 v7 = ((const float2*)(h + (size_t)ib.w * 128))[lane];
        ax0 += v0.x; ay0 += v0.y; ax1 += v1.x; ay1 += v1.y;
        ax2 += v2.x; ay2 += v2.y; ax3 += v3.x; ay3 += v3.y;
        ax0 += v4.x; ay0 += v4.y; ax1 += v5.x; ay1 += v5.y;
        ax2 += v6.x; ay2 += v6.y; ax3 += v7.x; ay3 += v7.y;
    }
    if (e + 4 <= n) {
        int4 ia = *(const int4*)(bk + e);
        float2 v0 = ((const float2*)(h + (size_t)ia.x * 128))[lane];
        float2 v1 = ((const float2*)(h + (size_t)ia.y * 128))[lane];
        float2 v2 = ((const float2*)(h + (size_t)ia.z * 128))[lane];
        float2 v3 = ((const float2*)(h + (size_t)ia.w * 128))[lane];
        ax0 += v0.x; ay0 += v0.y; ax1 += v1.x; ay1 += v1.y;
        ax2 += v2.x; ay2 += v2.y; ax3 += v3.x; ay3 += v3.y;
        e += 4;
    }
    for (; e < n; ++e) {
        int s = bk[e];
        float2 v = ((const float2*)(h + (size_t)s * 128))[lane];
        ax0 += v.x; ay0 += v.y;
    }
    float inv = 1.0f / fmaxf((float)deg, 1.0f);
    float2 r;
    r.x = ((ax0 + ax1) + (ax2 + ax3)) * inv;
    r.y = ((ay0 + ay1) + (ay2 + ay3)) * inv;
    ((float2*)(out + (size_t)wave * 128))[lane] = r;
}

// ---------------- fused layer-1 GEMM: h1 = relu(x@Ws + hn@Wn + b) ----------------
__global__ __launch_bounds__(256) void k_gemm1(const float* __restrict__ x,
                                               const float* __restrict__ hn,
                                               const float* __restrict__ Ws,
                                               const float* __restrict__ Wn,
                                               const float* __restrict__ b,
                                               float* __restrict__ out) {
    __shared__ float xs[32][128];
    __shared__ float hs[32][128];
    int tid = threadIdx.x;
    int row0 = blockIdx.x * 32;
    for (int i = tid; i < 32 * 32; i += 256) {
        int r = i >> 5, c4 = i & 31;
        int gr = row0 + r;
        float4 vx = make_float4(0.f, 0.f, 0.f, 0.f);
        float4 vh = vx;
        if (gr < N_NODES) {
            vx = ((const float4*)(x + (size_t)gr * 128))[c4];
            vh = ((const float4*)(hn + (size_t)gr * 128))[c4];
        }
        ((float4*)xs[r])[c4] = vx;
        ((float4*)hs[r])[c4] = vh;
    }
    __syncthreads();

    int tc = tid & 31;
    int tr = tid >> 5;
    float acc[4][4] = {};
    for (int k = 0; k < 128; k += 4) {
        float4 ws4[4], wn4[4];
#pragma unroll
        for (int kk = 0; kk < 4; ++kk) {
            ws4[kk] = ((const float4*)(Ws + (size_t)(k + kk) * 128))[tc];
            wn4[kk] = ((const float4*)(Wn + (size_t)(k + kk) * 128))[tc];
        }
        float4 xv[4], hv[4];
#pragma unroll
        for (int rr = 0; rr < 4; ++rr) {
            xv[rr] = *(const float4*)&xs[tr * 4 + rr][k];
            hv[rr] = *(const float4*)&hs[tr * 4 + rr][k];
        }
#pragma unroll
        for (int kk = 0; kk < 4; ++kk) {
#pragma unroll
            for (int rr = 0; rr < 4; ++rr) {
                float xvv = ((const float*)&xv[rr])[kk];
                float hvv = ((const float*)&hv[rr])[kk];
                acc[rr][0] += xvv * ((const float*)&ws4[kk])[0] + hvv * ((const float*)&wn4[kk])[0];
                acc[rr][1] += xvv * ((const float*)&ws4[kk])[1] + hvv * ((const float*)&wn4[kk])[1];
                acc[rr][2] += xvv * ((const float*)&ws4[kk])[2] + hvv * ((const float*)&wn4[kk])[2];
                acc[rr][3] += xvv * ((const float*)&ws4[kk])[3] + hvv * ((const float*)&wn4[kk])[3];
            }
        }
    }
    float4 bias = ((const float4*)b)[tc];
#pragma unroll
    for (int rr = 0; rr < 4; ++rr) {
        int gr = row0 + tr * 4 + rr;
        if (gr < N_NODES) {
            float4 o;
            o.x = fmaxf(acc[rr][0] + bias.x, 0.f);
            o.y = fmaxf(acc[rr][1] + bias.y, 0.f);
            o.z = fmaxf(acc[rr][2] + bias.z, 0.f);
            o.w = fmaxf(acc[rr][3] + bias.w, 0.f);
            ((float4*)(out + (size_t)gr * 128))[tc] = o;
        }
    }
}

// ---------------- fold layer-2 weights through the final projection ----------------
__global__ void k_combine(const float* __restrict__ W2s, const float* __restrict__ W2n,
                          const float* __restrict__ b2, const float* __restrict__ Wf,
                          const float* __restrict__ bf, float* __restrict__ wc) {
    int t = threadIdx.x;
    int k = t >> 1, c = t & 1;
    float s1 = 0.f, s2 = 0.f;
    for (int j = 0; j < 128; ++j) {
        float wf = Wf[j * 2 + c];
        s1 += W2s[k * 128 + j] * wf;
        s2 += W2n[k * 128 + j] * wf;
    }
    wc[k * 2 + c] = s1;
    wc[256 + k * 2 + c] = s2;
    if (t < 2) {
        float s = bf[t];
        for (int j = 0; j < 128; ++j) s += b2[j] * Wf[j * 2 + t];
        wc[512 + t] = s;
    }
}

// ---------------- fused aggregate(h1) + final projection ----------------
// out[n][c] = h1[n]:@Wcs[:,c] + mean_neigh(h1)[n]:@Wcn[:,c] + bc[c]
__global__ __launch_bounds__(256) void k_agg_final(const float* __restrict__ h1,
                                                   const int* __restrict__ cnt,
                                                   const int* __restrict__ bucket,
                                                   const float* __restrict__ wc,
                                                   float* __restrict__ out) {
    int wave = (int)((blockIdx.x * 256u + threadIdx.x) >> 6);
    int lane = threadIdx.x & 63;
    if (wave >= N_NODES) return;
    int deg = cnt[wave];
    int n = deg < CAP ? deg : CAP;
    const int* bk = bucket + (size_t)wave * CAP;
    float ax0 = 0.f, ay0 = 0.f, ax1 = 0.f, ay1 = 0.f;
    float ax2 = 0.f, ay2 = 0.f, ax3 = 0.f, ay3 = 0.f;
    int e = 0;
    for (; e + 8 <= n; e += 8) {
        int4 ia = *(const int4*)(bk + e);
        int4 ib = *(const int4*)(bk + e + 4);
        float2 v0 = ((const float2*)(h1 + (size_t)ia.x * 128))[lane];
        float2 v1 = ((const float2*)(h1 + (size_t)ia.y * 128))[lane];
        float2 v2 = ((const float2*)(h1 + (size_t)ia.z * 128))[lane];
        float2 v3 = ((const float2*)(h1 + (size_t)ia.w * 128))[lane];
        float2 v4 = ((const float2*)(h1 + (size_t)ib.x * 128))[lane];
        float2 v5 = ((const float2*)(h1 + (size_t)ib.y * 128))[lane];
        float2 v6 = ((const float2*)(h1 + (size_t)ib.z * 128))[lane];
        float2 v7 = ((const float2*)(h1 + (size_t)ib.w * 128))[lane];
        ax0 += v0.x; ay0 += v0.y; ax1 += v1.x; ay1 += v1.y;
        ax2 += v2.x; ay2 += v2.y; ax3 += v3.x; ay3 += v3.y;
        ax0 += v4.x; ay0 += v4.y; ax1 += v5.x; ay1 += v5.y;
        ax2 += v6.x; ay2 += v6.y; ax3 += v7.x; ay3 += v7.y;
    }
    if (e + 4 <= n) {
        int4 ia = *(const int4*)(bk + e);
        float2 v0 = ((const float2*)(h1 + (size_t)ia.x * 128))[lane];
        float2 v1 = ((const float2*)(h1 + (size_t)ia.y * 128))[lane];
        float2 v2 = ((const float2*)(h1 + (size_t)ia.z * 128))[lane];
        float2 v3 = ((const float2*)(h1 + (size_t)ia.w * 128))[lane];
        ax0 += v0.x; ay0 += v0.y; ax1 += v1.x; ay1 += v1.y;
        ax2 += v2.x; ay2 += v2.y; ax3 += v3.x; ay3 += v3.y;
        e += 4;
    }
    for (; e < n; ++e) {
        int s = bk[e];
        float2 v = ((const float2*)(h1 + (size_t)s * 128))[lane];
        ax0 += v.x; ay0 += v.y;
    }
    float inv = 1.0f / fmaxf((float)deg, 1.0f);
    float nx = ((ax0 + ax1) + (ax2 + ax3)) * inv;
    float ny = ((ay0 + ay1) + (ay2 + ay3)) * inv;

    float2 hv = ((const float2*)(h1 + (size_t)wave * 128))[lane];
    float2 ws0 = ((const float2*)wc)[2 * lane];
    float2 ws1 = ((const float2*)wc)[2 * lane + 1];
    float2 wn0 = ((const float2*)(wc + 256))[2 * lane];
    float2 wn1 = ((const float2*)(wc + 256))[2 * lane + 1];
    float p0 = hv.x * ws0.x + hv.y * ws1.x + nx * wn0.x + ny * wn1.x;
    float p1 = hv.x * ws0.y + hv.y * ws1.y + nx * wn0.y + ny * wn1.y;
#pragma unroll
    for (int off = 32; off >= 1; off >>= 1) {
        p0 += __shfl_xor(p0, off, 64);
        p1 += __shfl_xor(p1, off, 64);
    }
    if (lane == 0) {
        out[(size_t)wave * 2 + 0] = p0 + wc[512];
        out[(size_t)wave * 2 + 1] = p1 + wc[513];
    }
}

extern "C" void kernel_launch(void* const* d_in, const int* in_sizes, int n_in,
                              void* d_out, int out_size, void* d_ws, size_t ws_size,
                              hipStream_t stream) {
    const float* x   = (const float*)d_in[0];
    const int* esrc  = (const int*)d_in[1];
    const int* edst  = (const int*)d_in[2];
    const float* W1s = (const float*)d_in[3];
    const float* W1n = (const float*)d_in[4];
    const float* b1  = (const float*)d_in[5];
    const float* W2s = (const float*)d_in[6];
    const float* W2n = (const float*)d_in[7];
    const float* b2  = (const float*)d_in[8];
    const float* Wf  = (const float*)d_in[9];
    const float* bf  = (const float*)d_in[10];
    float* out = (float*)d_out;

    char* ws = (char*)d_ws;
    auto alloc = [&](size_t bytes) {
        char* p = ws;
        ws += (bytes + 255) & ~(size_t)255;
        return p;
    };
    int*   cnt    = (int*)  alloc((size_t)N_NODES * 4);
    int*   bucket = (int*)  alloc((size_t)N_NODES * CAP * 4);
    float* hn     = (float*)alloc((size_t)N_NODES * 128 * 4);
    float* h1     = (float*)alloc((size_t)N_NODES * 128 * 4);
    float* wc     = (float*)alloc(1024 * 4);

    hipMemsetAsync(cnt, 0, (size_t)N_NODES * 4, stream);
    k_build<<<(N_EDGES + 255) / 256, 256, 0, stream>>>(esrc, edst, cnt, bucket);
    k_aggregate<<<(N_NODES + 3) / 4, 256, 0, stream>>>(x, cnt, bucket, hn);
    k_gemm1<<<(N_NODES + 31) / 32, 256, 0, stream>>>(x, hn, W1s, W1n, b1, h1);
    k_combine<<<1, 256, 0, stream>>>(W2s, W2n, b2, Wf, bf, wc);
    k_agg_final<<<(N_NODES + 3) / 4, 256, 0, stream>>>(h1, cnt, bucket, wc, out);
}

// Round 3
// 176.890 us; speedup vs baseline: 1.7649x; 1.3727x over previous
//
#include <hip/hip_runtime.h>
#include <cstdint>
#include <cstddef>

#define N_NODES 50000
#define N_EDGES 800000
#define CAP 64   // max in-degree capacity; Binomial(800k,1/50k) mean 16 -> P(>64) ~ 1e-20

typedef __attribute__((ext_vector_type(8))) short bf16x8;   // 8 bf16 = 4 VGPRs (MFMA A/B frag)
typedef __attribute__((ext_vector_type(4))) float f32x4;    // MFMA C/D frag

__device__ __forceinline__ unsigned short f2bf(float f) {
    unsigned u = __builtin_bit_cast(unsigned, f);
    u += 0x7fff + ((u >> 16) & 1);          // round-to-nearest-even
    return (unsigned short)(u >> 16);
}
__device__ __forceinline__ float bflo(unsigned u) {   // low bf16 of packed pair -> f32
    return __builtin_bit_cast(float, u << 16);
}
__device__ __forceinline__ float bfhi(unsigned u) {   // high bf16 -> f32
    return __builtin_bit_cast(float, u & 0xffff0000u);
}

// ---------------- x (fp32) -> xb (bf16) ----------------
__global__ __launch_bounds__(256) void k_xtobf16(const float* __restrict__ x,
                                                 unsigned short* __restrict__ xb) {
    int i = blockIdx.x * 256 + threadIdx.x;   // one float4 per thread
    const int n4 = N_NODES * 128 / 4;
    if (i >= n4) return;
    float4 v = ((const float4*)x)[i];
    ushort4 o;
    o.x = f2bf(v.x); o.y = f2bf(v.y); o.z = f2bf(v.z); o.w = f2bf(v.w);
    ((ushort4*)xb)[i] = o;
}

// ---------------- bucket-CSR build ----------------
__global__ __launch_bounds__(256) void k_build(const int* __restrict__ src,
                                               const int* __restrict__ dst,
                                               int* __restrict__ cnt,
                                               int* __restrict__ bucket) {
    int e = blockIdx.x * 256 + threadIdx.x;
    if (e >= N_EDGES) return;
    int d = dst[e];
    int p = atomicAdd(&cnt[d], 1);
    if (p < CAP) bucket[(size_t)d * CAP + p] = src[e];
}

// ---------------- pull-style segment mean over bf16 rows: one wave per node ----------------
// lane handles feature pair (2*lane, 2*lane+1); 8-way unrolled edge loop for MLP
__global__ __launch_bounds__(256) void k_aggregate(const unsigned short* __restrict__ h,
                                                   const int* __restrict__ cnt,
                                                   const int* __restrict__ bucket,
                                                   unsigned short* __restrict__ out) {
    int wave = (int)((blockIdx.x * 256u + threadIdx.x) >> 6);
    int lane = threadIdx.x & 63;
    if (wave >= N_NODES) return;
    int deg = cnt[wave];
    int n = deg < CAP ? deg : CAP;
    const int* bk = bucket + (size_t)wave * CAP;
    float ax0 = 0.f, ay0 = 0.f, ax1 = 0.f, ay1 = 0.f;
    float ax2 = 0.f, ay2 = 0.f, ax3 = 0.f, ay3 = 0.f;
    int e = 0;
    for (; e + 8 <= n; e += 8) {
        int4 ia = *(const int4*)(bk + e);
        int4 ib = *(const int4*)(bk + e + 4);
        unsigned u0 = ((const unsigned*)(h + (size_t)ia.x * 128))[lane];
        unsigned u1 = ((const unsigned*)(h + (size_t)ia.y * 128))[lane];
        unsigned u2 = ((const unsigned*)(h + (size_t)ia.z * 128))[lane];
        unsigned u3 = ((const unsigned*)(h + (size_t)ia.w * 128))[lane];
        unsigned u4 = ((const unsigned*)(h + (size_t)ib.x * 128))[lane];
        unsigned u5 = ((const unsigned*)(h + (size_t)ib.y * 128))[lane];
        unsigned u6 = ((const unsigned*)(h + (size_t)ib.z * 128))[lane];
        unsigned u7 = ((const unsigned*)(h + (size_t)ib.w * 128))[lane];
        ax0 += bflo(u0); ay0 += bfhi(u0); ax1 += bflo(u1); ay1 += bfhi(u1);
        ax2 += bflo(u2); ay2 += bfhi(u2); ax3 += bflo(u3); ay3 += bfhi(u3);
        ax0 += bflo(u4); ay0 += bfhi(u4); ax1 += bflo(u5); ay1 += bfhi(u5);
        ax2 += bflo(u6); ay2 += bfhi(u6); ax3 += bflo(u7); ay3 += bfhi(u7);
    }
    if (e + 4 <= n) {
        int4 ia = *(const int4*)(bk + e);
        unsigned u0 = ((const unsigned*)(h + (size_t)ia.x * 128))[lane];
        unsigned u1 = ((const unsigned*)(h + (size_t)ia.y * 128))[lane];
        unsigned u2 = ((const unsigned*)(h + (size_t)ia.z * 128))[lane];
        unsigned u3 = ((const unsigned*)(h + (size_t)ia.w * 128))[lane];
        ax0 += bflo(u0); ay0 += bfhi(u0); ax1 += bflo(u1); ay1 += bfhi(u1);
        ax2 += bflo(u2); ay2 += bfhi(u2); ax3 += bflo(u3); ay3 += bfhi(u3);
        e += 4;
    }
    for (; e < n; ++e) {
        unsigned u = ((const unsigned*)(h + (size_t)bk[e] * 128))[lane];
        ax0 += bflo(u); ay0 += bfhi(u);
    }
    float inv = 1.0f / fmaxf((float)deg, 1.0f);
    float rx = ((ax0 + ax1) + (ax2 + ax3)) * inv;
    float ry = ((ay0 + ay1) + (ay2 + ay3)) * inv;
    unsigned o = (unsigned)f2bf(rx) | ((unsigned)f2bf(ry) << 16);
    ((unsigned*)(out + (size_t)wave * 128))[lane] = o;
}

// ---------------- pack [W1s;W1n] (fp32) into bf16 MFMA B-fragment layout ----------------
// wpack[((nt*8+ks)*64+lane)*8 + j] = Wcat[ks*32 + (lane>>4)*8 + j][nt*16 + (lane&15)]
__global__ __launch_bounds__(256) void k_pack_w(const float* __restrict__ W1s,
                                                const float* __restrict__ W1n,
                                                unsigned short* __restrict__ wpack) {
    int idx = blockIdx.x * 256 + threadIdx.x;   // 32768 total
    if (idx >= 8 * 8 * 64 * 8) return;
    int j = idx & 7;
    int lane = (idx >> 3) & 63;
    int ks = (idx >> 9) & 7;
    int nt = idx >> 12;
    int krow = ks * 32 + ((lane >> 4) << 3) + j;
    int col = nt * 16 + (lane & 15);
    float v = (krow < 128) ? W1s[krow * 128 + col] : W1n[(krow - 128) * 128 + col];
    wpack[idx] = f2bf(v);
}

// ---------------- layer-1 via MFMA: h1 = relu(x@W1s + hn@W1n + b1), bf16 out ----------------
// block = 4 waves; wave w owns rows [blk*64 + 16w, +16), full 128 cols, K=256 ([x|hn])
__global__ __launch_bounds__(256) void k_gemm1(const unsigned short* __restrict__ xb,
                                               const unsigned short* __restrict__ hnb,
                                               const unsigned short* __restrict__ wpack,
                                               const float* __restrict__ b1,
                                               unsigned short* __restrict__ h1b) {
    int wid = threadIdx.x >> 6;
    int lane = threadIdx.x & 63;
    int rowBase = blockIdx.x * 64 + wid * 16;
    int arow = rowBase + (lane & 15);
    if (arow >= N_NODES) arow = N_NODES - 1;       // tail clamp; stores guarded below
    int koff = (lane >> 4) << 3;                    // 0,8,16,24

    const unsigned short* xrow = xb + (size_t)arow * 128 + koff;
    const unsigned short* hrow = hnb + (size_t)arow * 128 + koff;
    bf16x8 a[8];
#pragma unroll
    for (int ks = 0; ks < 4; ++ks) a[ks] = *(const bf16x8*)(xrow + ks * 32);
#pragma unroll
    for (int ks = 0; ks < 4; ++ks) a[4 + ks] = *(const bf16x8*)(hrow + ks * 32);

    f32x4 acc[8] = {};
    const bf16x8* wp = (const bf16x8*)wpack + lane;
#pragma unroll
    for (int nt = 0; nt < 8; ++nt) {
#pragma unroll
        for (int ks = 0; ks < 8; ++ks) {
            bf16x8 bfrag = wp[(nt * 8 + ks) * 64];
            acc[nt] = __builtin_amdgcn_mfma_f32_16x16x32_bf16(a[ks], bfrag, acc[nt], 0, 0, 0);
        }
    }

    // C/D layout: col = lane&15, row = (lane>>4)*4 + reg   [m89-verified]
    int crow0 = rowBase + ((lane >> 4) << 2);
    int ccol = lane & 15;
#pragma unroll
    for (int nt = 0; nt < 8; ++nt) {
        int col = nt * 16 + ccol;
        float bias = b1[col];
#pragma unroll
        for (int r = 0; r < 4; ++r) {
            int row = crow0 + r;
            if (row < N_NODES) {
                float v = fmaxf(acc[nt][r] + bias, 0.f);
                h1b[(size_t)row * 128 + col] = f2bf(v);
            }
        }
    }
}

// ---------------- fold layer-2 weights through final projection (fp32) ----------------
// wc[0..255]=Wcs, [256..511]=Wcn, [512..513]=bc
__global__ __launch_bounds__(1024) void k_combine(const float* __restrict__ W2s,
                                                  const float* __restrict__ W2n,
                                                  const float* __restrict__ b2,
                                                  const float* __restrict__ Wf,
                                                  const float* __restrict__ bf,
                                                  float* __restrict__ wc) {
    __shared__ float r1[1024], r2[1024];
    int t = threadIdx.x;
    int kc = t & 255, k = kc >> 1, c = kc & 1;
    int jg = t >> 8;                       // 4-way K split
    float s1 = 0.f, s2 = 0.f;
    for (int j = jg * 32; j < jg * 32 + 32; ++j) {
        float wf = Wf[j * 2 + c];
        s1 += W2s[k * 128 + j] * wf;
        s2 += W2n[k * 128 + j] * wf;
    }
    r1[t] = s1; r2[t] = s2;
    __syncthreads();
    if (t < 256) {
        wc[k * 2 + c]       = (r1[t] + r1[t + 256]) + (r1[t + 512] + r1[t + 768]);
        wc[256 + k * 2 + c] = (r2[t] + r2[t + 256]) + (r2[t + 512] + r2[t + 768]);
    }
    if (t < 2) {
        float s = bf[t];
        for (int j = 0; j < 128; ++j) s += b2[j] * Wf[j * 2 + t];
        wc[512 + t] = s;
    }
}

// ---------------- fused aggregate(h1) + final projection ----------------
__global__ __launch_bounds__(256) void k_agg_final(const unsigned short* __restrict__ h1b,
                                                   const int* __restrict__ cnt,
                                                   const int* __restrict__ bucket,
                                                   const float* __restrict__ wc,
                                                   float* __restrict__ out) {
    int wave = (int)((blockIdx.x * 256u + threadIdx.x) >> 6);
    int lane = threadIdx.x & 63;
    if (wave >= N_NODES) return;
    int deg = cnt[wave];
    int n = deg < CAP ? deg : CAP;
    const int* bk = bucket + (size_t)wave * CAP;
    float ax0 = 0.f, ay0 = 0.f, ax1 = 0.f, ay1 = 0.f;
    float ax2 = 0.f, ay2 = 0.f, ax3 = 0.f, ay3 = 0.f;
    int e = 0;
    for (; e + 8 <= n; e += 8) {
        int4 ia = *(const int4*)(bk + e);
        int4 ib = *(const int4*)(bk + e + 4);
        unsigned u0 = ((const unsigned*)(h1b + (size_t)ia.x * 128))[lane];
        unsigned u1 = ((const unsigned*)(h1b + (size_t)ia.y * 128))[lane];
        unsigned u2 = ((const unsigned*)(h1b + (size_t)ia.z * 128))[lane];
        unsigned u3 = ((const unsigned*)(h1b + (size_t)ia.w * 128))[lane];
        unsigned u4 = ((const unsigned*)(h1b + (size_t)ib.x * 128))[lane];
        unsigned u5 = ((const unsigned*)(h1b + (size_t)ib.y * 128))[lane];
        unsigned u6 = ((const unsigned*)(h1b + (size_t)ib.z * 128))[lane];
        unsigned u7 = ((const unsigned*)(h1b + (size_t)ib.w * 128))[lane];
        ax0 += bflo(u0); ay0 += bfhi(u0); ax1 += bflo(u1); ay1 += bfhi(u1);
        ax2 += bflo(u2); ay2 += bfhi(u2); ax3 += bflo(u3); ay3 += bfhi(u3);
        ax0 += bflo(u4); ay0 += bfhi(u4); ax1 += bflo(u5); ay1 += bfhi(u5);
        ax2 += bflo(u6); ay2 += bfhi(u6); ax3 += bflo(u7); ay3 += bfhi(u7);
    }
    if (e + 4 <= n) {
        int4 ia = *(const int4*)(bk + e);
        unsigned u0 = ((const unsigned*)(h1b + (size_t)ia.x * 128))[lane];
        unsigned u1 = ((const unsigned*)(h1b + (size_t)ia.y * 128))[lane];
        unsigned u2 = ((const unsigned*)(h1b + (size_t)ia.z * 128))[lane];
        unsigned u3 = ((const unsigned*)(h1b + (size_t)ia.w * 128))[lane];
        ax0 += bflo(u0); ay0 += bfhi(u0); ax1 += bflo(u1); ay1 += bfhi(u1);
        ax2 += bflo(u2); ay2 += bfhi(u2); ax3 += bflo(u3); ay3 += bfhi(u3);
        e += 4;
    }
    for (; e < n; ++e) {
        unsigned u = ((const unsigned*)(h1b + (size_t)bk[e] * 128))[lane];
        ax0 += bflo(u); ay0 += bfhi(u);
    }
    float inv = 1.0f / fmaxf((float)deg, 1.0f);
    float nx = ((ax0 + ax1) + (ax2 + ax3)) * inv;
    float ny = ((ay0 + ay1) + (ay2 + ay3)) * inv;

    unsigned hu = ((const unsigned*)(h1b + (size_t)wave * 128))[lane];
    float hx = bflo(hu), hy = bfhi(hu);
    float2 ws0 = ((const float2*)wc)[2 * lane];
    float2 ws1 = ((const float2*)wc)[2 * lane + 1];
    float2 wn0 = ((const float2*)(wc + 256))[2 * lane];
    float2 wn1 = ((const float2*)(wc + 256))[2 * lane + 1];
    float p0 = hx * ws0.x + hy * ws1.x + nx * wn0.x + ny * wn1.x;
    float p1 = hx * ws0.y + hy * ws1.y + nx * wn0.y + ny * wn1.y;
#pragma unroll
    for (int off = 32; off >= 1; off >>= 1) {
        p0 += __shfl_xor(p0, off, 64);
        p1 += __shfl_xor(p1, off, 64);
    }
    if (lane == 0) {
        out[(size_t)wave * 2 + 0] = p0 + wc[512];
        out[(size_t)wave * 2 + 1] = p1 + wc[513];
    }
}

extern "C" void kernel_launch(void* const* d_in, const int* in_sizes, int n_in,
                              void* d_out, int out_size, void* d_ws, size_t ws_size,
                              hipStream_t stream) {
    const float* x   = (const float*)d_in[0];
    const int* esrc  = (const int*)d_in[1];
    const int* edst  = (const int*)d_in[2];
    const float* W1s = (const float*)d_in[3];
    const float* W1n = (const float*)d_in[4];
    const float* b1  = (const float*)d_in[5];
    const float* W2s = (const float*)d_in[6];
    const float* W2n = (const float*)d_in[7];
    const float* b2  = (const float*)d_in[8];
    const float* Wf  = (const float*)d_in[9];
    const float* bf  = (const float*)d_in[10];
    float* out = (float*)d_out;

    char* ws = (char*)d_ws;
    auto alloc = [&](size_t bytes) {
        char* p = ws;
        ws += (bytes + 255) & ~(size_t)255;
        return p;
    };
    int*            cnt    = (int*)           alloc((size_t)N_NODES * 4);
    int*            bucket = (int*)           alloc((size_t)N_NODES * CAP * 4);
    unsigned short* xb     = (unsigned short*)alloc((size_t)N_NODES * 128 * 2);
    unsigned short* hnb    = (unsigned short*)alloc((size_t)N_NODES * 128 * 2);
    unsigned short* h1b    = (unsigned short*)alloc((size_t)N_NODES * 128 * 2);
    unsigned short* wpack  = (unsigned short*)alloc(8 * 8 * 64 * 8 * 2);
    float*          wc     = (float*)         alloc(1024 * 4);

    hipMemsetAsync(cnt, 0, (size_t)N_NODES * 4, stream);
    k_xtobf16<<<(N_NODES * 128 / 4 + 255) / 256, 256, 0, stream>>>(x, xb);
    k_build<<<(N_EDGES + 255) / 256, 256, 0, stream>>>(esrc, edst, cnt, bucket);
    k_aggregate<<<(N_NODES + 3) / 4, 256, 0, stream>>>(xb, cnt, bucket, hnb);
    k_pack_w<<<(8 * 8 * 64 * 8 + 255) / 256, 256, 0, stream>>>(W1s, W1n, wpack);
    k_gemm1<<<(N_NODES + 63) / 64, 256, 0, stream>>>(xb, hnb, wpack, b1, h1b);
    k_combine<<<1, 1024, 0, stream>>>(W2s, W2n, b2, Wf, bf, wc);
    k_agg_final<<<(N_NODES + 3) / 4, 256, 0, stream>>>(h1b, cnt, bucket, wc, out);
}

// Round 4
// 137.666 us; speedup vs baseline: 2.2678x; 1.2849x over previous
//
#include <hip/hip_runtime.h>
#include <cstdint>
#include <cstddef>

#define N_NODES 50000
#define N_EDGES 800000
#define CAP 64   // max in-degree capacity; Binomial(800k,1/50k) mean 16 -> P(>64) ~ 1e-20

// prep mega-kernel block ranges
#define NB_BUILD 782                    // 1024 edges per block
#define NB_X     6250                   // 1024 floats per block
#define NB_PACK  128                    // 256 frag elems per block
#define NB_COMB  2
#define NB_PREP  (NB_BUILD + NB_X + NB_PACK + NB_COMB)

typedef __attribute__((ext_vector_type(8))) short bf16x8;   // MFMA A/B frag (4 VGPRs)
typedef __attribute__((ext_vector_type(4))) float f32x4;    // MFMA C/D frag

__device__ __forceinline__ unsigned short f2bf(float f) {
    unsigned u = __builtin_bit_cast(unsigned, f);
    u += 0x7fff + ((u >> 16) & 1);          // round-to-nearest-even
    return (unsigned short)(u >> 16);
}
__device__ __forceinline__ float bflo(unsigned u) { return __builtin_bit_cast(float, u << 16); }
__device__ __forceinline__ float bfhi(unsigned u) { return __builtin_bit_cast(float, u & 0xffff0000u); }

// ---------------- fused prep: build | xtobf16 | pack_w | combine ----------------
__global__ __launch_bounds__(256) void k_prep(const float* __restrict__ x,
                                              const int* __restrict__ src,
                                              const int* __restrict__ dst,
                                              const float* __restrict__ W1s,
                                              const float* __restrict__ W1n,
                                              const float* __restrict__ W2s,
                                              const float* __restrict__ W2n,
                                              const float* __restrict__ b2,
                                              const float* __restrict__ Wf,
                                              const float* __restrict__ bf,
                                              int* __restrict__ cnt,
                                              int* __restrict__ bucket,
                                              unsigned short* __restrict__ xb,
                                              unsigned short* __restrict__ wpack,
                                              float* __restrict__ wc) {
    int blk = blockIdx.x;
    int tid = threadIdx.x;

    if (blk < NB_BUILD) {
        // ---- bucket-CSR build: 4 consecutive edges per thread ----
        int e0 = (blk * 256 + tid) * 4;
        if (e0 >= N_EDGES) return;          // N_EDGES % 4 == 0 -> whole int4 valid
        int4 d4 = *(const int4*)(dst + e0);
        int4 s4 = *(const int4*)(src + e0);
        int p0 = atomicAdd(&cnt[d4.x], 1);
        int p1 = atomicAdd(&cnt[d4.y], 1);
        int p2 = atomicAdd(&cnt[d4.z], 1);
        int p3 = atomicAdd(&cnt[d4.w], 1);
        if (p0 < CAP) __builtin_nontemporal_store(s4.x, &bucket[(size_t)d4.x * CAP + p0]);
        if (p1 < CAP) __builtin_nontemporal_store(s4.y, &bucket[(size_t)d4.y * CAP + p1]);
        if (p2 < CAP) __builtin_nontemporal_store(s4.z, &bucket[(size_t)d4.z * CAP + p2]);
        if (p3 < CAP) __builtin_nontemporal_store(s4.w, &bucket[(size_t)d4.w * CAP + p3]);
    } else if (blk < NB_BUILD + NB_X) {
        // ---- x (fp32) -> xb (bf16), one float4 per thread ----
        int i = (blk - NB_BUILD) * 256 + tid;
        const int n4 = N_NODES * 128 / 4;
        if (i >= n4) return;
        float4 v = ((const float4*)x)[i];
        ushort4 o;
        o.x = f2bf(v.x); o.y = f2bf(v.y); o.z = f2bf(v.z); o.w = f2bf(v.w);
        ((ushort4*)xb)[i] = o;
    } else if (blk < NB_BUILD + NB_X + NB_PACK) {
        // ---- pack [W1s;W1n] into bf16 MFMA B-fragment layout ----
        int idx = (blk - NB_BUILD - NB_X) * 256 + tid;   // 32768 total
        int j = idx & 7;
        int lane = (idx >> 3) & 63;
        int ks = (idx >> 9) & 7;
        int nt = idx >> 12;
        int krow = ks * 32 + ((lane >> 4) << 3) + j;
        int col = nt * 16 + (lane & 15);
        float v = (krow < 128) ? W1s[krow * 128 + col] : W1n[(krow - 128) * 128 + col];
        wpack[idx] = f2bf(v);
    } else {
        // ---- fold layer-2 weights through final projection (fp32) ----
        // wc[0..255]=Wcs[k][c], [256..511]=Wcn[k][c], [512..513]=bc
        int role = blk - NB_BUILD - NB_X - NB_PACK;   // 0: Wcs, 1: Wcn + bc
        int k = tid >> 1, c = tid & 1;
        const float* W = role == 0 ? W2s : W2n;
        float s = 0.f;
        for (int j = 0; j < 128; ++j) s += W[k * 128 + j] * Wf[j * 2 + c];
        wc[role * 256 + k * 2 + c] = s;
        if (role == 1 && tid < 2) {
            float sb = bf[tid];
            for (int j = 0; j < 128; ++j) sb += b2[j] * Wf[j * 2 + tid];
            wc[512 + tid] = sb;
        }
    }
}

// ---------------- pull-style segment mean over bf16 rows: one wave per node ----------------
// lane handles feature pair (2*lane, 2*lane+1); 16-deep MLP on the edge loop
__global__ __launch_bounds__(256) void k_aggregate(const unsigned short* __restrict__ h,
                                                   const int* __restrict__ cnt,
                                                   const int* __restrict__ bucket,
                                                   unsigned short* __restrict__ out) {
    int wave = (int)((blockIdx.x * 256u + threadIdx.x) >> 6);
    int lane = threadIdx.x & 63;
    if (wave >= N_NODES) return;
    int deg = cnt[wave];
    int n = deg < CAP ? deg : CAP;
    const int* bk = bucket + (size_t)wave * CAP;
    float ax0 = 0.f, ay0 = 0.f, ax1 = 0.f, ay1 = 0.f;
    float ax2 = 0.f, ay2 = 0.f, ax3 = 0.f, ay3 = 0.f;
    int e = 0;
    for (; e + 16 <= n; e += 16) {
        int4 i0 = *(const int4*)(bk + e);
        int4 i1 = *(const int4*)(bk + e + 4);
        int4 i2 = *(const int4*)(bk + e + 8);
        int4 i3 = *(const int4*)(bk + e + 12);
        unsigned u0  = ((const unsigned*)(h + (size_t)i0.x * 128))[lane];
        unsigned u1  = ((const unsigned*)(h + (size_t)i0.y * 128))[lane];
        unsigned u2  = ((const unsigned*)(h + (size_t)i0.z * 128))[lane];
        unsigned u3  = ((const unsigned*)(h + (size_t)i0.w * 128))[lane];
        unsigned u4  = ((const unsigned*)(h + (size_t)i1.x * 128))[lane];
        unsigned u5  = ((const unsigned*)(h + (size_t)i1.y * 128))[lane];
        unsigned u6  = ((const unsigned*)(h + (size_t)i1.z * 128))[lane];
        unsigned u7  = ((const unsigned*)(h + (size_t)i1.w * 128))[lane];
        unsigned u8  = ((const unsigned*)(h + (size_t)i2.x * 128))[lane];
        unsigned u9  = ((const unsigned*)(h + (size_t)i2.y * 128))[lane];
        unsigned u10 = ((const unsigned*)(h + (size_t)i2.z * 128))[lane];
        unsigned u11 = ((const unsigned*)(h + (size_t)i2.w * 128))[lane];
        unsigned u12 = ((const unsigned*)(h + (size_t)i3.x * 128))[lane];
        unsigned u13 = ((const unsigned*)(h + (size_t)i3.y * 128))[lane];
        unsigned u14 = ((const unsigned*)(h + (size_t)i3.z * 128))[lane];
        unsigned u15 = ((const unsigned*)(h + (size_t)i3.w * 128))[lane];
        ax0 += bflo(u0);  ay0 += bfhi(u0);  ax1 += bflo(u1);  ay1 += bfhi(u1);
        ax2 += bflo(u2);  ay2 += bfhi(u2);  ax3 += bflo(u3);  ay3 += bfhi(u3);
        ax0 += bflo(u4);  ay0 += bfhi(u4);  ax1 += bflo(u5);  ay1 += bfhi(u5);
        ax2 += bflo(u6);  ay2 += bfhi(u6);  ax3 += bflo(u7);  ay3 += bfhi(u7);
        ax0 += bflo(u8);  ay0 += bfhi(u8);  ax1 += bflo(u9);  ay1 += bfhi(u9);
        ax2 += bflo(u10); ay2 += bfhi(u10); ax3 += bflo(u11); ay3 += bfhi(u11);
        ax0 += bflo(u12); ay0 += bfhi(u12); ax1 += bflo(u13); ay1 += bfhi(u13);
        ax2 += bflo(u14); ay2 += bfhi(u14); ax3 += bflo(u15); ay3 += bfhi(u15);
    }
    if (e + 8 <= n) {
        int4 i0 = *(const int4*)(bk + e);
        int4 i1 = *(const int4*)(bk + e + 4);
        unsigned u0 = ((const unsigned*)(h + (size_t)i0.x * 128))[lane];
        unsigned u1 = ((const unsigned*)(h + (size_t)i0.y * 128))[lane];
        unsigned u2 = ((const unsigned*)(h + (size_t)i0.z * 128))[lane];
        unsigned u3 = ((const unsigned*)(h + (size_t)i0.w * 128))[lane];
        unsigned u4 = ((const unsigned*)(h + (size_t)i1.x * 128))[lane];
        unsigned u5 = ((const unsigned*)(h + (size_t)i1.y * 128))[lane];
        unsigned u6 = ((const unsigned*)(h + (size_t)i1.z * 128))[lane];
        unsigned u7 = ((const unsigned*)(h + (size_t)i1.w * 128))[lane];
        ax0 += bflo(u0); ay0 += bfhi(u0); ax1 += bflo(u1); ay1 += bfhi(u1);
        ax2 += bflo(u2); ay2 += bfhi(u2); ax3 += bflo(u3); ay3 += bfhi(u3);
        ax0 += bflo(u4); ay0 += bfhi(u4); ax1 += bflo(u5); ay1 += bfhi(u5);
        ax2 += bflo(u6); ay2 += bfhi(u6); ax3 += bflo(u7); ay3 += bfhi(u7);
        e += 8;
    }
    if (e + 4 <= n) {
        int4 i0 = *(const int4*)(bk + e);
        unsigned u0 = ((const unsigned*)(h + (size_t)i0.x * 128))[lane];
        unsigned u1 = ((const unsigned*)(h + (size_t)i0.y * 128))[lane];
        unsigned u2 = ((const unsigned*)(h + (size_t)i0.z * 128))[lane];
        unsigned u3 = ((const unsigned*)(h + (size_t)i0.w * 128))[lane];
        ax0 += bflo(u0); ay0 += bfhi(u0); ax1 += bflo(u1); ay1 += bfhi(u1);
        ax2 += bflo(u2); ay2 += bfhi(u2); ax3 += bflo(u3); ay3 += bfhi(u3);
        e += 4;
    }
    for (; e < n; ++e) {
        unsigned u = ((const unsigned*)(h + (size_t)bk[e] * 128))[lane];
        ax0 += bflo(u); ay0 += bfhi(u);
    }
    float inv = 1.0f / fmaxf((float)deg, 1.0f);
    float rx = ((ax0 + ax1) + (ax2 + ax3)) * inv;
    float ry = ((ay0 + ay1) + (ay2 + ay3)) * inv;
    unsigned o = (unsigned)f2bf(rx) | ((unsigned)f2bf(ry) << 16);
    ((unsigned*)(out + (size_t)wave * 128))[lane] = o;
}

// ---------------- layer-1 MFMA GEMM + fused layer-2 projections ----------------
// h1 = relu(x@W1s + hn@W1n + b1) stays in registers; writes pq[row] = {h1@Wcs, h1@Wcn}
__global__ __launch_bounds__(256) void k_gemm1(const unsigned short* __restrict__ xb,
                                               const unsigned short* __restrict__ hnb,
                                               const unsigned short* __restrict__ wpack,
                                               const float* __restrict__ b1,
                                               const float* __restrict__ wc,
                                               float* __restrict__ pq) {
    int wid = threadIdx.x >> 6;
    int lane = threadIdx.x & 63;
    int l15 = lane & 15;
    int rowBase = blockIdx.x * 64 + wid * 16;
    int arow = rowBase + l15;
    if (arow >= N_NODES) arow = N_NODES - 1;       // tail clamp; stores guarded below
    int koff = (lane >> 4) << 3;                    // 0,8,16,24

    const unsigned short* xrow = xb + (size_t)arow * 128 + koff;
    const unsigned short* hrow = hnb + (size_t)arow * 128 + koff;
    bf16x8 a[8];
#pragma unroll
    for (int ks = 0; ks < 4; ++ks) a[ks] = *(const bf16x8*)(xrow + ks * 32);
#pragma unroll
    for (int ks = 0; ks < 4; ++ks) a[4 + ks] = *(const bf16x8*)(hrow + ks * 32);

    f32x4 acc[8] = {};
    const bf16x8* wp = (const bf16x8*)wpack + lane;
#pragma unroll
    for (int nt = 0; nt < 8; ++nt) {
#pragma unroll
        for (int ks = 0; ks < 8; ++ks) {
            bf16x8 bfrag = wp[(nt * 8 + ks) * 64];
            acc[nt] = __builtin_amdgcn_mfma_f32_16x16x32_bf16(a[ks], bfrag, acc[nt], 0, 0, 0);
        }
    }

    // h1 values in-register: acc[nt][r] = relu(acc + bias), col = nt*16 + l15
#pragma unroll
    for (int nt = 0; nt < 8; ++nt) {
        float bias = b1[nt * 16 + l15];
#pragma unroll
        for (int r = 0; r < 4; ++r) acc[nt][r] = fmaxf(acc[nt][r] + bias, 0.f);
    }

    // folded layer-2 weights for this lane's columns
    float2 wcs[8], wcn[8];
#pragma unroll
    for (int nt = 0; nt < 8; ++nt) {
        wcs[nt] = *(const float2*)(wc + (size_t)(nt * 16 + l15) * 2);
        wcn[nt] = *(const float2*)(wc + 256 + (size_t)(nt * 16 + l15) * 2);
    }

    // per-row 128-dots: reduce partial sums across the 16 lanes of each row group
#pragma unroll
    for (int r = 0; r < 4; ++r) {
        float p0 = 0.f, p1 = 0.f, q0 = 0.f, q1 = 0.f;
#pragma unroll
        for (int nt = 0; nt < 8; ++nt) {
            float v = acc[nt][r];
            p0 += v * wcs[nt].x; p1 += v * wcs[nt].y;
            q0 += v * wcn[nt].x; q1 += v * wcn[nt].y;
        }
#pragma unroll
        for (int off = 1; off < 16; off <<= 1) {
            p0 += __shfl_xor(p0, off, 64);
            p1 += __shfl_xor(p1, off, 64);
            q0 += __shfl_xor(q0, off, 64);
            q1 += __shfl_xor(q1, off, 64);
        }
        int row = rowBase + ((lane >> 4) << 2) + r;
        if (l15 == 0 && row < N_NODES) {
            float4 o; o.x = p0; o.y = p1; o.z = q0; o.w = q1;
            ((float4*)pq)[row] = o;
        }
    }
}

// ---------------- final: out[n] = pq[n].p + mean_src(pq[src].q) + bc ----------------
__global__ __launch_bounds__(256) void k_final(const float* __restrict__ pq,
                                               const int* __restrict__ cnt,
                                               const int* __restrict__ bucket,
                                               const float* __restrict__ wc,
                                               float* __restrict__ out) {
    int wave = (int)((blockIdx.x * 256u + threadIdx.x) >> 6);
    int lane = threadIdx.x & 63;
    if (wave >= N_NODES) return;
    int deg = cnt[wave];
    int n = deg < CAP ? deg : CAP;
    float qx = 0.f, qy = 0.f;
    if (lane < n) {
        int s = bucket[(size_t)wave * CAP + lane];
        float2 q = *(const float2*)(pq + (size_t)s * 4 + 2);
        qx = q.x; qy = q.y;
    }
#pragma unroll
    for (int off = 32; off >= 1; off >>= 1) {
        qx += __shfl_xor(qx, off, 64);
        qy += __shfl_xor(qy, off, 64);
    }
    if (lane == 0) {
        float inv = 1.0f / fmaxf((float)deg, 1.0f);
        float2 p = *(const float2*)(pq + (size_t)wave * 4);
        out[(size_t)wave * 2 + 0] = p.x + qx * inv + wc[512];
        out[(size_t)wave * 2 + 1] = p.y + qy * inv + wc[513];
    }
}

extern "C" void kernel_launch(void* const* d_in, const int* in_sizes, int n_in,
                              void* d_out, int out_size, void* d_ws, size_t ws_size,
                              hipStream_t stream) {
    const float* x   = (const float*)d_in[0];
    const int* esrc  = (const int*)d_in[1];
    const int* edst  = (const int*)d_in[2];
    const float* W1s = (const float*)d_in[3];
    const float* W1n = (const float*)d_in[4];
    const float* b1  = (const float*)d_in[5];
    const float* W2s = (const float*)d_in[6];
    const float* W2n = (const float*)d_in[7];
    const float* b2  = (const float*)d_in[8];
    const float* Wf  = (const float*)d_in[9];
    const float* bf  = (const float*)d_in[10];
    float* out = (float*)d_out;

    char* ws = (char*)d_ws;
    auto alloc = [&](size_t bytes) {
        char* p = ws;
        ws += (bytes + 255) & ~(size_t)255;
        return p;
    };
    int*            cnt    = (int*)           alloc((size_t)N_NODES * 4);
    int*            bucket = (int*)           alloc((size_t)N_NODES * CAP * 4);
    unsigned short* xb     = (unsigned short*)alloc((size_t)N_NODES * 128 * 2);
    unsigned short* hnb    = (unsigned short*)alloc((size_t)N_NODES * 128 * 2);
    float*          pq     = (float*)         alloc((size_t)N_NODES * 4 * 4);
    unsigned short* wpack  = (unsigned short*)alloc(8 * 8 * 64 * 8 * 2);
    float*          wc     = (float*)         alloc(1024 * 4);

    hipMemsetAsync(cnt, 0, (size_t)N_NODES * 4, stream);
    k_prep<<<NB_PREP, 256, 0, stream>>>(x, esrc, edst, W1s, W1n, W2s, W2n, b2, Wf, bf,
                                        cnt, bucket, xb, wpack, wc);
    k_aggregate<<<(N_NODES + 3) / 4, 256, 0, stream>>>(xb, cnt, bucket, hnb);
    k_gemm1<<<(N_NODES + 63) / 64, 256, 0, stream>>>(xb, hnb, wpack, b1, wc, pq);
    k_final<<<(N_NODES + 3) / 4, 256, 0, stream>>>(pq, cnt, bucket, wc, out);
}

// Round 5
// 112.810 us; speedup vs baseline: 2.7675x; 1.2203x over previous
//
#include <hip/hip_runtime.h>
#include <cstdint>
#include <cstddef>

#define N_NODES 50000
#define N_EDGES 800000
#define CAP 64        // max in-degree capacity; Binomial(800k,1/50k) mean 16 -> P(>64) ~ 1e-20

// XCD-sharded build geometry
#define SHARDS 8
#define SHARD_SZ 6250                 // N_NODES / SHARDS
#define CHUNK_EDGES 8192              // edges per chunk (256 thr * 4 * 8 iters)
#define N_CHUNKS 98                   // ceil(800000 / 8192)
#define NB_BUILD (N_CHUNKS * SHARDS)  // 784

// prep mega-kernel block ranges
#define NB_X     6250                 // 1024 floats per block
#define NB_PACK  128                  // 256 frag elems per block
#define NB_COMB  2
#define NB_PREP  (NB_BUILD + NB_X + NB_PACK + NB_COMB)

typedef __attribute__((ext_vector_type(8))) short bf16x8;   // MFMA A/B frag (4 VGPRs)
typedef __attribute__((ext_vector_type(4))) float f32x4;    // MFMA C/D frag

__device__ __forceinline__ unsigned short f2bf(float f) {
    unsigned u = __builtin_bit_cast(unsigned, f);
    u += 0x7fff + ((u >> 16) & 1);          // round-to-nearest-even
    return (unsigned short)(u >> 16);
}
__device__ __forceinline__ float bflo(unsigned u) { return __builtin_bit_cast(float, u << 16); }
__device__ __forceinline__ float bfhi(unsigned u) { return __builtin_bit_cast(float, u & 0xffff0000u); }

// ---------------- fused prep: sharded build | xtobf16 | pack_w | combine ----------------
__global__ __launch_bounds__(256) void k_prep(const float* __restrict__ x,
                                              const int* __restrict__ src,
                                              const int* __restrict__ dst,
                                              const float* __restrict__ W1s,
                                              const float* __restrict__ W1n,
                                              const float* __restrict__ W2s,
                                              const float* __restrict__ W2n,
                                              const float* __restrict__ b2,
                                              const float* __restrict__ Wf,
                                              const float* __restrict__ bf,
                                              int* __restrict__ cnt,
                                              int* __restrict__ bucket,
                                              unsigned short* __restrict__ xb,
                                              unsigned short* __restrict__ wpack,
                                              float* __restrict__ wc) {
    int blk = blockIdx.x;
    int tid = threadIdx.x;

    if (blk < NB_BUILD) {
        // ---- XCD-sharded bucket-CSR build ----
        // shard = blk % 8 tracks the round-robin block->XCD mapping (perf heuristic
        // only): all atomics/stores for a dst-range stay in one XCD's L2.
        int shard = blk & 7;
        int chunk = blk >> 3;
        int lo = shard * SHARD_SZ;
        int hi = lo + SHARD_SZ;          // N_NODES == SHARDS*SHARD_SZ exactly
        int base = chunk * CHUNK_EDGES;
#pragma unroll
        for (int i = 0; i < CHUNK_EDGES / 1024; ++i) {
            int e0 = base + (i * 256 + tid) * 4;
            if (e0 >= N_EDGES) break;                    // N_EDGES % 4 == 0
            int4 d4 = *(const int4*)(dst + e0);
            int4 s4 = *(const int4*)(src + e0);
            if (d4.x >= lo && d4.x < hi) { int p = atomicAdd(&cnt[d4.x], 1); if (p < CAP) bucket[(size_t)d4.x * CAP + p] = s4.x; }
            if (d4.y >= lo && d4.y < hi) { int p = atomicAdd(&cnt[d4.y], 1); if (p < CAP) bucket[(size_t)d4.y * CAP + p] = s4.y; }
            if (d4.z >= lo && d4.z < hi) { int p = atomicAdd(&cnt[d4.z], 1); if (p < CAP) bucket[(size_t)d4.z * CAP + p] = s4.z; }
            if (d4.w >= lo && d4.w < hi) { int p = atomicAdd(&cnt[d4.w], 1); if (p < CAP) bucket[(size_t)d4.w * CAP + p] = s4.w; }
        }
    } else if (blk < NB_BUILD + NB_X) {
        // ---- x (fp32) -> xb (bf16), one float4 per thread ----
        int i = (blk - NB_BUILD) * 256 + tid;
        const int n4 = N_NODES * 128 / 4;
        if (i >= n4) return;
        float4 v = ((const float4*)x)[i];
        ushort4 o;
        o.x = f2bf(v.x); o.y = f2bf(v.y); o.z = f2bf(v.z); o.w = f2bf(v.w);
        ((ushort4*)xb)[i] = o;
    } else if (blk < NB_BUILD + NB_X + NB_PACK) {
        // ---- pack [W1s;W1n] into bf16 MFMA B-fragment layout ----
        int idx = (blk - NB_BUILD - NB_X) * 256 + tid;   // 32768 total
        int j = idx & 7;
        int lane = (idx >> 3) & 63;
        int ks = (idx >> 9) & 7;
        int nt = idx >> 12;
        int krow = ks * 32 + ((lane >> 4) << 3) + j;
        int col = nt * 16 + (lane & 15);
        float v = (krow < 128) ? W1s[krow * 128 + col] : W1n[(krow - 128) * 128 + col];
        wpack[idx] = f2bf(v);
    } else {
        // ---- fold layer-2 weights through final projection (fp32) ----
        // wc[0..255]=Wcs[k][c], [256..511]=Wcn[k][c], [512..513]=bc
        int role = blk - NB_BUILD - NB_X - NB_PACK;   // 0: Wcs, 1: Wcn + bc
        int k = tid >> 1, c = tid & 1;
        const float* W = role == 0 ? W2s : W2n;
        float s = 0.f;
        for (int j = 0; j < 128; ++j) s += W[k * 128 + j] * Wf[j * 2 + c];
        wc[role * 256 + k * 2 + c] = s;
        if (role == 1 && tid < 2) {
            float sb = bf[tid];
            for (int j = 0; j < 128; ++j) sb += b2[j] * Wf[j * 2 + tid];
            wc[512 + tid] = sb;
        }
    }
}

// ---------------- pull-style segment mean over bf16 rows: one wave per node ----------------
// lane handles feature pair (2*lane, 2*lane+1); 16-deep MLP on the edge loop
__global__ __launch_bounds__(256) void k_aggregate(const unsigned short* __restrict__ h,
                                                   const int* __restrict__ cnt,
                                                   const int* __restrict__ bucket,
                                                   unsigned short* __restrict__ out) {
    int wave = (int)((blockIdx.x * 256u + threadIdx.x) >> 6);
    int lane = threadIdx.x & 63;
    if (wave >= N_NODES) return;
    int deg = cnt[wave];
    int n = deg < CAP ? deg : CAP;
    const int* bk = bucket + (size_t)wave * CAP;
    float ax0 = 0.f, ay0 = 0.f, ax1 = 0.f, ay1 = 0.f;
    float ax2 = 0.f, ay2 = 0.f, ax3 = 0.f, ay3 = 0.f;
    int e = 0;
    for (; e + 16 <= n; e += 16) {
        int4 i0 = *(const int4*)(bk + e);
        int4 i1 = *(const int4*)(bk + e + 4);
        int4 i2 = *(const int4*)(bk + e + 8);
        int4 i3 = *(const int4*)(bk + e + 12);
        unsigned u0  = ((const unsigned*)(h + (size_t)i0.x * 128))[lane];
        unsigned u1  = ((const unsigned*)(h + (size_t)i0.y * 128))[lane];
        unsigned u2  = ((const unsigned*)(h + (size_t)i0.z * 128))[lane];
        unsigned u3  = ((const unsigned*)(h + (size_t)i0.w * 128))[lane];
        unsigned u4  = ((const unsigned*)(h + (size_t)i1.x * 128))[lane];
        unsigned u5  = ((const unsigned*)(h + (size_t)i1.y * 128))[lane];
        unsigned u6  = ((const unsigned*)(h + (size_t)i1.z * 128))[lane];
        unsigned u7  = ((const unsigned*)(h + (size_t)i1.w * 128))[lane];
        unsigned u8  = ((const unsigned*)(h + (size_t)i2.x * 128))[lane];
        unsigned u9  = ((const unsigned*)(h + (size_t)i2.y * 128))[lane];
        unsigned u10 = ((const unsigned*)(h + (size_t)i2.z * 128))[lane];
        unsigned u11 = ((const unsigned*)(h + (size_t)i2.w * 128))[lane];
        unsigned u12 = ((const unsigned*)(h + (size_t)i3.x * 128))[lane];
        unsigned u13 = ((const unsigned*)(h + (size_t)i3.y * 128))[lane];
        unsigned u14 = ((const unsigned*)(h + (size_t)i3.z * 128))[lane];
        unsigned u15 = ((const unsigned*)(h + (size_t)i3.w * 128))[lane];
        ax0 += bflo(u0);  ay0 += bfhi(u0);  ax1 += bflo(u1);  ay1 += bfhi(u1);
        ax2 += bflo(u2);  ay2 += bfhi(u2);  ax3 += bflo(u3);  ay3 += bfhi(u3);
        ax0 += bflo(u4);  ay0 += bfhi(u4);  ax1 += bflo(u5);  ay1 += bfhi(u5);
        ax2 += bflo(u6);  ay2 += bfhi(u6);  ax3 += bflo(u7);  ay3 += bfhi(u7);
        ax0 += bflo(u8);  ay0 += bfhi(u8);  ax1 += bflo(u9);  ay1 += bfhi(u9);
        ax2 += bflo(u10); ay2 += bfhi(u10); ax3 += bflo(u11); ay3 += bfhi(u11);
        ax0 += bflo(u12); ay0 += bfhi(u12); ax1 += bflo(u13); ay1 += bfhi(u13);
        ax2 += bflo(u14); ay2 += bfhi(u14); ax3 += bflo(u15); ay3 += bfhi(u15);
    }
    if (e + 8 <= n) {
        int4 i0 = *(const int4*)(bk + e);
        int4 i1 = *(const int4*)(bk + e + 4);
        unsigned u0 = ((const unsigned*)(h + (size_t)i0.x * 128))[lane];
        unsigned u1 = ((const unsigned*)(h + (size_t)i0.y * 128))[lane];
        unsigned u2 = ((const unsigned*)(h + (size_t)i0.z * 128))[lane];
        unsigned u3 = ((const unsigned*)(h + (size_t)i0.w * 128))[lane];
        unsigned u4 = ((const unsigned*)(h + (size_t)i1.x * 128))[lane];
        unsigned u5 = ((const unsigned*)(h + (size_t)i1.y * 128))[lane];
        unsigned u6 = ((const unsigned*)(h + (size_t)i1.z * 128))[lane];
        unsigned u7 = ((const unsigned*)(h + (size_t)i1.w * 128))[lane];
        ax0 += bflo(u0); ay0 += bfhi(u0); ax1 += bflo(u1); ay1 += bfhi(u1);
        ax2 += bflo(u2); ay2 += bfhi(u2); ax3 += bflo(u3); ay3 += bfhi(u3);
        ax0 += bflo(u4); ay0 += bfhi(u4); ax1 += bflo(u5); ay1 += bfhi(u5);
        ax2 += bflo(u6); ay2 += bfhi(u6); ax3 += bflo(u7); ay3 += bfhi(u7);
        e += 8;
    }
    if (e + 4 <= n) {
        int4 i0 = *(const int4*)(bk + e);
        unsigned u0 = ((const unsigned*)(h + (size_t)i0.x * 128))[lane];
        unsigned u1 = ((const unsigned*)(h + (size_t)i0.y * 128))[lane];
        unsigned u2 = ((const unsigned*)(h + (size_t)i0.z * 128))[lane];
        unsigned u3 = ((const unsigned*)(h + (size_t)i0.w * 128))[lane];
        ax0 += bflo(u0); ay0 += bfhi(u0); ax1 += bflo(u1); ay1 += bfhi(u1);
        ax2 += bflo(u2); ay2 += bfhi(u2); ax3 += bflo(u3); ay3 += bfhi(u3);
        e += 4;
    }
    for (; e < n; ++e) {
        unsigned u = ((const unsigned*)(h + (size_t)bk[e] * 128))[lane];
        ax0 += bflo(u); ay0 += bfhi(u);
    }
    float inv = 1.0f / fmaxf((float)deg, 1.0f);
    float rx = ((ax0 + ax1) + (ax2 + ax3)) * inv;
    float ry = ((ay0 + ay1) + (ay2 + ay3)) * inv;
    unsigned o = (unsigned)f2bf(rx) | ((unsigned)f2bf(ry) << 16);
    ((unsigned*)(out + (size_t)wave * 128))[lane] = o;
}

// ---------------- layer-1 MFMA GEMM + fused layer-2 projections ----------------
// h1 = relu(x@W1s + hn@W1n + b1) stays in registers; writes pq[row] = {h1@Wcs, h1@Wcn}
__global__ __launch_bounds__(256) void k_gemm1(const unsigned short* __restrict__ xb,
                                               const unsigned short* __restrict__ hnb,
                                               const unsigned short* __restrict__ wpack,
                                               const float* __restrict__ b1,
                                               const float* __restrict__ wc,
                                               float* __restrict__ pq) {
    int wid = threadIdx.x >> 6;
    int lane = threadIdx.x & 63;
    int l15 = lane & 15;
    int rowBase = blockIdx.x * 64 + wid * 16;
    int arow = rowBase + l15;
    if (arow >= N_NODES) arow = N_NODES - 1;       // tail clamp; stores guarded below
    int koff = (lane >> 4) << 3;                    // 0,8,16,24

    const unsigned short* xrow = xb + (size_t)arow * 128 + koff;
    const unsigned short* hrow = hnb + (size_t)arow * 128 + koff;
    bf16x8 a[8];
#pragma unroll
    for (int ks = 0; ks < 4; ++ks) a[ks] = *(const bf16x8*)(xrow + ks * 32);
#pragma unroll
    for (int ks = 0; ks < 4; ++ks) a[4 + ks] = *(const bf16x8*)(hrow + ks * 32);

    f32x4 acc[8] = {};
    const bf16x8* wp = (const bf16x8*)wpack + lane;
#pragma unroll
    for (int nt = 0; nt < 8; ++nt) {
#pragma unroll
        for (int ks = 0; ks < 8; ++ks) {
            bf16x8 bfrag = wp[(nt * 8 + ks) * 64];
            acc[nt] = __builtin_amdgcn_mfma_f32_16x16x32_bf16(a[ks], bfrag, acc[nt], 0, 0, 0);
        }
    }

    // h1 values in-register: acc[nt][r] = relu(acc + bias), col = nt*16 + l15
#pragma unroll
    for (int nt = 0; nt < 8; ++nt) {
        float bias = b1[nt * 16 + l15];
#pragma unroll
        for (int r = 0; r < 4; ++r) acc[nt][r] = fmaxf(acc[nt][r] + bias, 0.f);
    }

    // folded layer-2 weights for this lane's columns
    float2 wcs[8], wcn[8];
#pragma unroll
    for (int nt = 0; nt < 8; ++nt) {
        wcs[nt] = *(const float2*)(wc + (size_t)(nt * 16 + l15) * 2);
        wcn[nt] = *(const float2*)(wc + 256 + (size_t)(nt * 16 + l15) * 2);
    }

    // per-row 128-dots: reduce partial sums across the 16 lanes of each row group
#pragma unroll
    for (int r = 0; r < 4; ++r) {
        float p0 = 0.f, p1 = 0.f, q0 = 0.f, q1 = 0.f;
#pragma unroll
        for (int nt = 0; nt < 8; ++nt) {
            float v = acc[nt][r];
            p0 += v * wcs[nt].x; p1 += v * wcs[nt].y;
            q0 += v * wcn[nt].x; q1 += v * wcn[nt].y;
        }
#pragma unroll
        for (int off = 1; off < 16; off <<= 1) {
            p0 += __shfl_xor(p0, off, 64);
            p1 += __shfl_xor(p1, off, 64);
            q0 += __shfl_xor(q0, off, 64);
            q1 += __shfl_xor(q1, off, 64);
        }
        int row = rowBase + ((lane >> 4) << 2) + r;
        if (l15 == 0 && row < N_NODES) {
            float4 o; o.x = p0; o.y = p1; o.z = q0; o.w = q1;
            ((float4*)pq)[row] = o;
        }
    }
}

// ---------------- final: out[n] = pq[n].p + mean_src(pq[src].q) + bc ----------------
__global__ __launch_bounds__(256) void k_final(const float* __restrict__ pq,
                                               const int* __restrict__ cnt,
                                               const int* __restrict__ bucket,
                                               const float* __restrict__ wc,
                                               float* __restrict__ out) {
    int wave = (int)((blockIdx.x * 256u + threadIdx.x) >> 6);
    int lane = threadIdx.x & 63;
    if (wave >= N_NODES) return;
    int deg = cnt[wave];
    int n = deg < CAP ? deg : CAP;
    float qx = 0.f, qy = 0.f;
    if (lane < n) {
        int s = bucket[(size_t)wave * CAP + lane];
        float2 q = *(const float2*)(pq + (size_t)s * 4 + 2);
        qx = q.x; qy = q.y;
    }
#pragma unroll
    for (int off = 32; off >= 1; off >>= 1) {
        qx += __shfl_xor(qx, off, 64);
        qy += __shfl_xor(qy, off, 64);
    }
    if (lane == 0) {
        float inv = 1.0f / fmaxf((float)deg, 1.0f);
        float2 p = *(const float2*)(pq + (size_t)wave * 4);
        out[(size_t)wave * 2 + 0] = p.x + qx * inv + wc[512];
        out[(size_t)wave * 2 + 1] = p.y + qy * inv + wc[513];
    }
}

extern "C" void kernel_launch(void* const* d_in, const int* in_sizes, int n_in,
                              void* d_out, int out_size, void* d_ws, size_t ws_size,
                              hipStream_t stream) {
    const float* x   = (const float*)d_in[0];
    const int* esrc  = (const int*)d_in[1];
    const int* edst  = (const int*)d_in[2];
    const float* W1s = (const float*)d_in[3];
    const float* W1n = (const float*)d_in[4];
    const float* b1  = (const float*)d_in[5];
    const float* W2s = (const float*)d_in[6];
    const float* W2n = (const float*)d_in[7];
    const float* b2  = (const float*)d_in[8];
    const float* Wf  = (const float*)d_in[9];
    const float* bf  = (const float*)d_in[10];
    float* out = (float*)d_out;

    char* ws = (char*)d_ws;
    auto alloc = [&](size_t bytes) {
        char* p = ws;
        ws += (bytes + 255) & ~(size_t)255;
        return p;
    };
    int*            cnt    = (int*)           alloc((size_t)N_NODES * 4);
    int*            bucket = (int*)           alloc((size_t)N_NODES * CAP * 4);
    unsigned short* xb     = (unsigned short*)alloc((size_t)N_NODES * 128 * 2);
    unsigned short* hnb    = (unsigned short*)alloc((size_t)N_NODES * 128 * 2);
    float*          pq     = (float*)         alloc((size_t)N_NODES * 4 * 4);
    unsigned short* wpack  = (unsigned short*)alloc(8 * 8 * 64 * 8 * 2);
    float*          wc     = (float*)         alloc(1024 * 4);

    hipMemsetAsync(cnt, 0, (size_t)N_NODES * 4, stream);
    k_prep<<<NB_PREP, 256, 0, stream>>>(x, esrc, edst, W1s, W1n, W2s, W2n, b2, Wf, bf,
                                        cnt, bucket, xb, wpack, wc);
    k_aggregate<<<(N_NODES + 3) / 4, 256, 0, stream>>>(xb, cnt, bucket, hnb);
    k_gemm1<<<(N_NODES + 63) / 64, 256, 0, stream>>>(xb, hnb, wpack, b1, wc, pq);
    k_final<<<(N_NODES + 3) / 4, 256, 0, stream>>>(pq, cnt, bucket, wc, out);
}